// Round 6
// baseline (132.119 us; speedup 1.0000x reference)
//
#include <hip/hip_runtime.h>
#include <float.h>

// loss = (1/(E(E-1))) * sum_{i,j: t_i != t_j} relu(pred[i,t_j] - (f_own[j]-1)) / (N[t_i] N[t_j])
// Per class c (sorted thresholds + prefix sums): row i contribution from class c is
//   k*p - prefix[k], k = #{thr < p}, p = pred[i,c].
// (thr,pref) interleaved float2; 4-level register search tree (pinned) + 2 parallel
// ds_read_b64 for the final level; row-side (target,invN) staged per block.

#define CCLS 1000
#define PAD 64      // global slots per class (supports class count <= 63)
#define LSLOT 32    // LDS slots per class (fast path: count <= 31; else global fallback)
#define TPB 1024
#define CCH 250     // classes per chunk -> 4 chunks
#define NCH 4
#define NRBLK 128   // row blocks per chunk
#define LSTR 257    // LDS class stride (dword-pair banks spread)
#define RMAX 256    // max rows per block staged (RPB = 96 here)

__global__ __launch_bounds__(1024) void k_prep(const int* __restrict__ target, int B,
        int* ncnt, float* invN, int* fill, float* scal, int* flags) {
    __shared__ int h[CCLS];
    __shared__ int esh, mx;
    int tid = threadIdx.x;
    if (tid < CCLS) h[tid] = 0;
    if (tid == 0) { esh = 0; mx = 0; }
    __syncthreads();
    for (int j = tid; j < B; j += TPB) atomicAdd(&h[target[j]], 1);
    __syncthreads();
    if (tid < CCLS) {
        int n = h[tid];
        ncnt[tid] = n;
        invN[tid] = n ? 1.0f / (float)n : 0.f;
        fill[tid] = 0;
        if (n) atomicAdd(&esh, 1);
        atomicMax(&mx, n);
    }
    __syncthreads();
    if (tid == 0) {
        scal[0] = (float)esh;   // E
        scal[1] = 0.f;          // accumulator
        flags[0] = 0;           // k_main completion counter
        flags[1] = (mx > LSLOT - 1) ? 1 : 0;  // overflow -> global fallback path
    }
}

__global__ void k_scatter(const float* __restrict__ pred, const int* __restrict__ target,
                          int* fill, float2* pairP, int B) {
    int j = blockIdx.x * 256 + threadIdx.x;
    if (j >= B) return;
    int tj = target[j];
    float fo = pred[(size_t)j * CCLS + tj];  // f_own[j]
    int pos = atomicAdd(&fill[tj], 1);
    if (pos < PAD) pairP[tj * PAD + pos] = make_float2(fo - 1.0f, 0.f);
}

// wave-per-class rank sort + prefix via shuffles; fills all PAD slots (FLT_MAX pad, pref pad = total)
__global__ __launch_bounds__(256) void k_sortpfx(const int* __restrict__ ncnt,
                                                 float2* pairP) {
    int c = (blockIdx.x * 256 + threadIdx.x) >> 6;
    int lane = threadIdx.x & 63;
    if (c >= CCLS) return;
    int cnt = min(ncnt[c], PAD - 1);
    int base = c * PAD;
    float v = (lane < cnt) ? pairP[base + lane].x : FLT_MAX;
    int rank = 0;
    float psum = 0.f, tot = 0.f;
    for (int k = 0; k < cnt; ++k) {
        float u = __shfl(v, k);
        bool sm = (u < v) || (u == v && k < lane);
        rank += sm ? 1 : 0;
        psum += sm ? u : 0.f;
        tot += u;
    }
    if (lane < cnt) pairP[base + rank] = make_float2(v, psum);
    else            pairP[base + lane] = make_float2(FLT_MAX, tot);
}

__global__ __launch_bounds__(TPB) void k_main(const float* __restrict__ pred,
        const int* __restrict__ target, const float2* __restrict__ pairP,
        const float* __restrict__ invN,
        float* scal, int* flags, float* __restrict__ out, int B, int RPB) {
    __shared__ float2 pairL[LSLOT][LSTR];
    __shared__ float2 rowWT[RMAX];
    __shared__ float redL[TPB / 64];

    const int tid = threadIdx.x;
    const int chunk = blockIdx.x / NRBLK;
    const int rblk = blockIdx.x % NRBLK;
    const int c0 = chunk * CCH;
    const int rbase = rblk * RPB;
    const int ovf = flags[1];
    const int rows = min(min(RPB, B - rbase), RMAX);

    // stage (thr,pref) pairs: coalesced 8B global reads, transposed [k][cc] in LDS
    for (int g = tid; g < CCH * LSLOT; g += TPB) {
        int cc = g >> 5, k = g & 31;
        pairL[k][cc] = pairP[(size_t)(c0 + cc) * PAD + k];
    }
    // stage row-side (target, invN[target])
    for (int r = tid; r < rows; r += TPB) {
        int t = target[rbase + r];
        rowWT[r] = make_float2(__int_as_float(t), invN[t]);
    }
    __syncthreads();

    const int rr = tid >> 8;        // 0..3: row phase
    const int cc = tid & 255;       // class within chunk
    const bool cvalid = cc < CCH;
    const int ccS = cvalid ? cc : 0;      // clamp so invalid lanes read real (finite) data
    const int c = c0 + ccS;
    const float invc = cvalid ? invN[c] : 0.f;   // invalid lanes contribute 0

    float acc = 0.f;
    if (!ovf) {
        // levels 1-4 of the 32-slot search tree in registers, pinned against remat
        float e1  = pairL[1][ccS].x,  e3  = pairL[3][ccS].x;
        float e5  = pairL[5][ccS].x,  e7  = pairL[7][ccS].x;
        float e9  = pairL[9][ccS].x,  e11 = pairL[11][ccS].x;
        float e13 = pairL[13][ccS].x, e15 = pairL[15][ccS].x;
        float e17 = pairL[17][ccS].x, e19 = pairL[19][ccS].x;
        float e21 = pairL[21][ccS].x, e23 = pairL[23][ccS].x;
        float e25 = pairL[25][ccS].x, e27 = pairL[27][ccS].x;
        float e29 = pairL[29][ccS].x;
        asm volatile("" : "+v"(e1), "+v"(e3), "+v"(e5), "+v"(e7), "+v"(e9),
                          "+v"(e11), "+v"(e13), "+v"(e15), "+v"(e17), "+v"(e19),
                          "+v"(e21), "+v"(e23), "+v"(e25), "+v"(e27), "+v"(e29));

        auto tree = [&](float p) -> int {
            const bool b1 = e15 < p;
            const float t2 = b1 ? e23 : e7;
            const bool b2 = t2 < p;
            const float t3 = b1 ? (b2 ? e27 : e19) : (b2 ? e11 : e3);
            const bool b3 = t3 < p;
            const float t4 = b1 ? (b2 ? (b3 ? e29 : e25) : (b3 ? e21 : e17))
                                : (b2 ? (b3 ? e13 : e9)  : (b3 ? e5  : e1));
            const bool b4 = t4 < p;
            return (b1 ? 16 : 0) + (b2 ? 8 : 0) + (b3 ? 4 : 0) + (b4 ? 2 : 0);
        };
        auto fin = [&](float p, int lo, float2 qa, float2 qb, float2 wt) -> float {
            const bool b5 = qa.x < p;
            const float lof = (float)lo + (b5 ? 1.f : 0.f);
            const float pf = b5 ? qb.y : qa.y;
            const float contrib = lof * p - pf;
            const int ti = __float_as_int(wt.x);
            const float w = (c != ti) ? invc * wt.y : 0.f;
            return contrib * w;
        };

        const float* pc = pred + c;
        const int full = rows >> 4;   // 16-row groups (4 rows per phase-thread)
        for (int it = 0; it < full; ++it) {
            const int r0 = it * 16 + rr;
            // 4 independent coalesced loads
            const float p0 = pc[(size_t)(rbase + r0)      * CCLS];
            const float p1 = pc[(size_t)(rbase + r0 + 4)  * CCLS];
            const float p2 = pc[(size_t)(rbase + r0 + 8)  * CCLS];
            const float p3 = pc[(size_t)(rbase + r0 + 12) * CCLS];
            // 4 independent register trees
            const int l0 = tree(p0), l1 = tree(p1), l2 = tree(p2), l3 = tree(p3);
            // 8 independent pair gathers (ds_read_b64)
            const float2 a0 = pairL[l0][ccS], q0 = pairL[l0 + 1][ccS];
            const float2 a1 = pairL[l1][ccS], q1 = pairL[l1 + 1][ccS];
            const float2 a2 = pairL[l2][ccS], q2 = pairL[l2 + 1][ccS];
            const float2 a3 = pairL[l3][ccS], q3 = pairL[l3 + 1][ccS];
            // broadcast row data
            const float2 w0 = rowWT[r0],      w1 = rowWT[r0 + 4];
            const float2 w2 = rowWT[r0 + 8],  w3 = rowWT[r0 + 12];
            acc += fin(p0, l0, a0, q0, w0);
            acc += fin(p1, l1, a1, q1, w1);
            acc += fin(p2, l2, a2, q2, w2);
            acc += fin(p3, l3, a3, q3, w3);
        }
        // tail rows
        for (int r = full * 16 + rr; r < rows; r += 4) {
            const float p = pc[(size_t)(rbase + r) * CCLS];
            const int lo = tree(p);
            const float2 qa = pairL[lo][ccS], qb = pairL[lo + 1][ccS];
            acc += fin(p, lo, qa, qb, rowWT[r]);
        }
    } else {
        // correctness fallback (class count > 31): 6-level search in global padded segment
        const float2* seg = pairP + (size_t)c * PAD;
        for (int r = rr; r < rows; r += 4) {
            const float2 wt = rowWT[r];
            const float p = pred[(size_t)(rbase + r) * CCLS + c];
            int lo = 0;
#pragma unroll
            for (int s = 32; s; s >>= 1) lo += (seg[lo + s - 1].x < p) ? s : 0;
            const float contrib = (float)lo * p - seg[lo].y;
            const int ti = __float_as_int(wt.x);
            const float w = (c != ti) ? invc * wt.y : 0.f;
            acc = fmaf(contrib, w, acc);
        }
    }

    for (int o = 32; o; o >>= 1) acc += __shfl_down(acc, o);
    if ((tid & 63) == 0) redL[tid >> 6] = acc;
    __syncthreads();
    if (tid == 0) {
        float ssum = 0.f;
#pragma unroll
        for (int k = 0; k < TPB / 64; ++k) ssum += redL[k];
        atomicAdd(&scal[1], ssum);
        __threadfence();
        int done = atomicAdd(&flags[0], 1);
        if (done == (int)gridDim.x - 1) {   // last block finalizes
            float tot = atomicAdd(&scal[1], 0.f);
            float E = scal[0];
            out[0] = tot / (E * (E - 1.0f));
        }
    }
}

extern "C" void kernel_launch(void* const* d_in, const int* in_sizes, int n_in,
                              void* d_out, int out_size, void* d_ws, size_t ws_size,
                              hipStream_t stream) {
    const float* pred = (const float*)d_in[0];
    const int* target = (const int*)d_in[1];
    const int B = in_sizes[1];  // 12288

    char* ws = (char*)d_ws;
    int* ncnt    = (int*)(ws + 0);        // 1000 ints
    float* invN  = (float*)(ws + 4096);   // 1000 floats
    int* fill    = (int*)(ws + 8192);     // 1000 ints
    float* scal  = (float*)(ws + 12288);  // [0]=E, [1]=acc
    int* flags   = (int*)(ws + 12352);    // [0]=counter, [1]=overflow
    float2* pairP = (float2*)(ws + 16384); // 1000*64 float2 (512KB), (thr,pref) interleaved

    const int gb = (B + 255) / 256;
    const int RPB = (B + NRBLK - 1) / NRBLK;

    k_prep<<<1, TPB, 0, stream>>>(target, B, ncnt, invN, fill, scal, flags);
    k_scatter<<<gb, 256, 0, stream>>>(pred, target, fill, pairP, B);
    k_sortpfx<<<(CCLS * 64 + 255) / 256, 256, 0, stream>>>(ncnt, pairP);
    k_main<<<NCH * NRBLK, TPB, 0, stream>>>(pred, target, pairP, invN,
                                            scal, flags, (float*)d_out, B, RPB);
}

// Round 7
// 64.291 us; speedup vs baseline: 2.0550x; 2.0550x over previous
//
#include <hip/hip_runtime.h>
#include <float.h>

// loss = (1/(E(E-1))) * sum_{i,j: t_i != t_j} relu(pred[i,t_j] - (f_own[j]-1)) / (N[t_i] N[t_j])
// Per class c (sorted thresholds + prefix sums): contribution of (i,c) = k*p - pref[k],
// k = #{thr < p}, p = pred[i,c]. Diagonal (c == t_i) terms are summed analytically in
// k_sortpfx and subtracted once, so the hot loop has no exclusion test.
// Search: levels 1-4 in registers (volatile-pinned LDS reads), level 5 + prefix via ONE
// ds_read_b128 of the interleaved (thr,pref) candidate pair. pref[base+2] = q.w + q.z.

#define CCLS 1000
#define PAD 64      // global float2 slots per class (supports count <= 63)
#define TPB 1024
#define CCH 250     // classes per chunk -> 4 chunks
#define NCH 4
#define NRBLK 128   // row blocks per chunk (RPB = 96)
#define CSTR 34     // LDS float2 stride per class: 272 B -> 16B-aligned quads, even bank spread
#define RMAX 128

__global__ __launch_bounds__(1024) void k_prep(const int* __restrict__ target, int B,
        int* ncnt, float* invN, int* fill, float* scal, int* flags) {
    __shared__ int h[CCLS];
    __shared__ int esh, mx;
    int tid = threadIdx.x;
    if (tid < CCLS) h[tid] = 0;
    if (tid == 0) { esh = 0; mx = 0; }
    __syncthreads();
    for (int j = tid; j < B; j += TPB) atomicAdd(&h[target[j]], 1);
    __syncthreads();
    if (tid < CCLS) {
        int n = h[tid];
        ncnt[tid] = n;
        invN[tid] = n ? 1.0f / (float)n : 0.f;
        fill[tid] = 0;
        if (n) atomicAdd(&esh, 1);
        atomicMax(&mx, n);
    }
    __syncthreads();
    if (tid == 0) {
        scal[0] = (float)esh;   // E
        scal[1] = 0.f;          // main accumulator
        scal[2] = 0.f;          // diagonal accumulator
        flags[0] = 0;           // k_main completion counter
        flags[1] = (mx > 31) ? 1 : 0;  // overflow -> global fallback path
    }
}

__global__ void k_scatter(const float* __restrict__ pred, const int* __restrict__ target,
                          int* fill, float2* pairP, int B) {
    int j = blockIdx.x * 256 + threadIdx.x;
    if (j >= B) return;
    int tj = target[j];
    float fo = pred[(size_t)j * CCLS + tj];  // f_own[j]
    int pos = atomicAdd(&fill[tj], 1);
    if (pos < PAD) pairP[tj * PAD + pos] = make_float2(fo - 1.0f, 0.f);
}

// wave-per-class rank sort + prefix via shuffles; fills all PAD slots (FLT_MAX pad, pref pad = total).
// Also accumulates the diagonal sum D = sum_c sum_{i: t_i=c} F_c(f_own_i) / N_c^2 into scal[2].
__global__ __launch_bounds__(256) void k_sortpfx(const int* __restrict__ ncnt,
                                                 float2* pairP, float* scal) {
    int c = (blockIdx.x * 256 + threadIdx.x) >> 6;
    int lane = threadIdx.x & 63;
    if (c >= CCLS) return;
    int cnt = min(ncnt[c], PAD - 1);
    int base = c * PAD;
    float v = (lane < cnt) ? pairP[base + lane].x : FLT_MAX;
    float vp1 = v + 1.0f;           // f_own of this element
    int rank = 0, rank2 = 0;
    float psum = 0.f, tot = 0.f, psum2 = 0.f;
    for (int k = 0; k < cnt; ++k) {
        float u = __shfl(v, k);
        bool sm = (u < v) || (u == v && k < lane);
        rank += sm ? 1 : 0;
        psum += sm ? u : 0.f;
        tot += u;
        bool sm2 = (u < vp1);       // for F_c(f_own) = rank2*(v+1) - psum2
        rank2 += sm2 ? 1 : 0;
        psum2 += sm2 ? u : 0.f;
    }
    if (lane < cnt) pairP[base + rank] = make_float2(v, psum);
    else            pairP[base + lane] = make_float2(FLT_MAX, tot);
    // diagonal contribution
    float F = (lane < cnt) ? ((float)rank2 * vp1 - psum2) : 0.f;
    for (int o = 32; o; o >>= 1) F += __shfl_down(F, o);
    if (lane == 0 && cnt > 0) {
        float ic = 1.0f / (float)cnt;
        atomicAdd(&scal[2], F * ic * ic);
    }
}

__global__ __launch_bounds__(TPB) void k_main(const float* __restrict__ pred,
        const int* __restrict__ target, const float2* __restrict__ pairP,
        const float* __restrict__ invN,
        float* scal, int* flags, float* __restrict__ out, int B, int RPB) {
    __shared__ float2 pairC[CCH][CSTR];   // 250*34*8 = 68000 B
    __shared__ float rowW[RMAX];
    __shared__ float redL[TPB / 64];

    const int tid = threadIdx.x;
    const int chunk = blockIdx.x / NRBLK;
    const int rblk = blockIdx.x % NRBLK;
    const int c0 = chunk * CCH;
    const int rbase = rblk * RPB;
    const int ovf = flags[1];
    const int rows = min(min(RPB, B - rbase), RMAX);

    // stage (thr,pref): coalesced 8B global reads, class-contiguous LDS (stride 34 float2)
    for (int g = tid; g < CCH * 32; g += TPB) {
        int cc = g >> 5, k = g & 31;
        pairC[cc][k] = pairP[(size_t)(c0 + cc) * PAD + k];
    }
    for (int r = tid; r < rows; r += TPB) rowW[r] = invN[target[rbase + r]];
    __syncthreads();

    const int rr = tid >> 8;        // 0..3: row phase
    const int cc = tid & 255;       // class within chunk
    const bool cvalid = cc < CCH;
    const int ccS = cvalid ? cc : 0;
    const int c = c0 + ccS;
    const float invc = cvalid ? invN[c] : 0.f;   // zeroes invalid lanes at the end

    const int nit = (rows > rr) ? ((rows - rr + 3) >> 2) : 0;

    float acc = 0.f;
    if (!ovf) {
        // levels 1-4: thr at sorted odd indices 1..29. volatile => loaded exactly once,
        // cannot be rematerialized as in-loop LDS reads.
        const volatile float* tf = (const volatile float*)&pairC[ccS][0];
        const float e1  = tf[2],  e3  = tf[6],  e5  = tf[10], e7  = tf[14];
        const float e9  = tf[18], e11 = tf[22], e13 = tf[26], e15 = tf[30];
        const float e17 = tf[34], e19 = tf[38], e21 = tf[42], e23 = tf[46];
        const float e25 = tf[50], e27 = tf[54], e29 = tf[58];

        const char* ldsb = (const char*)&pairC[0][0] + ccS * (CSTR * 8);
        const float* pp = pred + (size_t)(rbase + rr) * CCLS + c;

        for (int it = 0; it < nit; ++it) {
            const float p = *pp;
            pp += 4 * CCLS;
            const float wt = rowW[it * 4 + rr];

            const bool b1 = e15 < p;
            const float t2 = b1 ? e23 : e7;
            const bool b2 = t2 < p;
            const float t3 = b1 ? (b2 ? e27 : e19) : (b2 ? e11 : e3);
            const bool b3 = t3 < p;
            const float t4 = b1 ? (b2 ? (b3 ? e29 : e25) : (b3 ? e21 : e17))
                                : (b2 ? (b3 ? e13 : e9)  : (b3 ? e5  : e1));
            const bool b4 = t4 < p;
            const int basep = (b1 ? 16 : 0) + (b2 ? 8 : 0) + (b3 ? 4 : 0) + (b4 ? 2 : 0);

            // one 16B-aligned b128: (thr[b], pref[b], thr[b+1], pref[b+1])
            const float4 q = *(const float4*)(ldsb + basep * 8);
            const bool h0 = q.x < p;
            const bool h1 = q.z < p;
            const int k = basep + (h0 ? 1 : 0) + (h1 ? 1 : 0);
            const float pf = h1 ? (q.w + q.z) : (h0 ? q.w : q.y);
            const float contrib = fmaf((float)k, p, -pf);
            acc = fmaf(contrib, wt, acc);
        }
    } else {
        // correctness fallback (some class count in 32..63): 6-level search in global segment
        const float2* seg = pairP + (size_t)c * PAD;
        for (int it = 0; it < nit; ++it) {
            const int i = rbase + it * 4 + rr;
            const float p = pred[(size_t)i * CCLS + c];
            const float wt = rowW[it * 4 + rr];
            int lo = 0;
#pragma unroll
            for (int s = 32; s; s >>= 1) lo += (seg[lo + s - 1].x < p) ? s : 0;
            const float contrib = (float)lo * p - seg[lo].y;
            acc = fmaf(contrib, wt, acc);
        }
    }
    acc *= invc;

    for (int o = 32; o; o >>= 1) acc += __shfl_down(acc, o);
    if ((tid & 63) == 0) redL[tid >> 6] = acc;
    __syncthreads();
    if (tid == 0) {
        float ssum = 0.f;
#pragma unroll
        for (int k = 0; k < TPB / 64; ++k) ssum += redL[k];
        atomicAdd(&scal[1], ssum);
        __threadfence();
        int done = atomicAdd(&flags[0], 1);
        if (done == (int)gridDim.x - 1) {   // last block finalizes
            float tot = atomicAdd(&scal[1], 0.f);
            float D = scal[2];
            float E = scal[0];
            out[0] = (tot - D) / (E * (E - 1.0f));
        }
    }
}

extern "C" void kernel_launch(void* const* d_in, const int* in_sizes, int n_in,
                              void* d_out, int out_size, void* d_ws, size_t ws_size,
                              hipStream_t stream) {
    const float* pred = (const float*)d_in[0];
    const int* target = (const int*)d_in[1];
    const int B = in_sizes[1];  // 12288

    char* ws = (char*)d_ws;
    int* ncnt    = (int*)(ws + 0);        // 1000 ints
    float* invN  = (float*)(ws + 4096);   // 1000 floats
    int* fill    = (int*)(ws + 8192);     // 1000 ints
    float* scal  = (float*)(ws + 12288);  // [0]=E, [1]=acc, [2]=diag
    int* flags   = (int*)(ws + 12352);    // [0]=counter, [1]=overflow
    float2* pairP = (float2*)(ws + 16384); // 1000*64 float2 (512KB), (thr,pref)

    const int gb = (B + 255) / 256;
    const int RPB = (B + NRBLK - 1) / NRBLK;

    k_prep<<<1, TPB, 0, stream>>>(target, B, ncnt, invN, fill, scal, flags);
    k_scatter<<<gb, 256, 0, stream>>>(pred, target, fill, pairP, B);
    k_sortpfx<<<(CCLS * 64 + 255) / 256, 256, 0, stream>>>(ncnt, pairP, scal);
    k_main<<<NCH * NRBLK, TPB, 0, stream>>>(pred, target, pairP, invN,
                                            scal, flags, (float*)d_out, B, RPB);
}